// Round 2
// baseline (186.123 us; speedup 1.0000x reference)
//
#include <hip/hip_runtime.h>

#define IN_DIM   4096
#define OUT_DIM  4096
#define FAN_IN   64
#define ROWS     8                       // batch rows staged per block
#define NTHREADS 512
#define O_PER_THREAD (OUT_DIM / NTHREADS) // 8 output columns per thread

// Bijective 16B-block swizzle: within each 8-col group, XOR low bits by group id.
// Spreads ds bank-start groups for both staging writes and gather reads.
__device__ __forceinline__ int bswz(int m) {
    return (m & ~7) | ((m ^ (m >> 3)) & 7);
}

// round-to-nearest-even-ish f32->bf16, packed pair (a=lo, b=hi)
__device__ __forceinline__ unsigned int pack_bf16(float a, float b) {
    unsigned int ua = __float_as_uint(a);
    ua += 0x7FFFu + ((ua >> 16) & 1u);
    unsigned int ub = __float_as_uint(b);
    ub += 0x7FFFu + ((ub >> 16) & 1u);
    return (ua >> 16) | (ub & 0xFFFF0000u);
}

__global__ __launch_bounds__(NTHREADS, 4)
void ffi_sparse_kernel(const float* __restrict__ inp,
                       const float* __restrict__ W,
                       const int*   __restrict__ M,
                       const float* __restrict__ bias,
                       float* __restrict__ out)
{
    // [col][8 rows] as packed bf16 pairs: 4 uints (16 B) per column. 64 KiB.
    __shared__ unsigned int lds[IN_DIM * ROWS / 2];

    const int tid = threadIdx.x;
    const int r0  = blockIdx.x * ROWS;

    // ---------------- stage: 8 rows x 4096 cols, f32 -> bf16, transpose ----------------
    // Each iteration handles a 4x4 tile (4 rows x 4 cols = 16 elements).
    // Total tiles = ROWS*IN_DIM/16 = 2048 -> 4 iterations at 512 threads.
    #pragma unroll
    for (int t = 0; t < (ROWS * IN_DIM / 16) / NTHREADS; ++t) {   // 4 iterations
        const int tile = tid + t * NTHREADS;     // 0..2047
        const int rblk = tile >> 10;             // 0..1 -> rows rblk*4 .. rblk*4+3
        const int c4   = (tile & 1023) << 2;     // column base 0..4092
        const float* src = inp + (size_t)(r0 + rblk * 4) * IN_DIM + c4;
        const float4 v0 = *(const float4*)(src);
        const float4 v1 = *(const float4*)(src + IN_DIM);
        const float4 v2 = *(const float4*)(src + 2 * IN_DIM);
        const float4 v3 = *(const float4*)(src + 3 * IN_DIM);

        unsigned int* p;
        p = lds + bswz(c4 + 0) * 4 + rblk * 2;
        *(uint2*)p = make_uint2(pack_bf16(v0.x, v1.x), pack_bf16(v2.x, v3.x));
        p = lds + bswz(c4 + 1) * 4 + rblk * 2;
        *(uint2*)p = make_uint2(pack_bf16(v0.y, v1.y), pack_bf16(v2.y, v3.y));
        p = lds + bswz(c4 + 2) * 4 + rblk * 2;
        *(uint2*)p = make_uint2(pack_bf16(v0.z, v1.z), pack_bf16(v2.z, v3.z));
        p = lds + bswz(c4 + 3) * 4 + rblk * 2;
        *(uint2*)p = make_uint2(pack_bf16(v0.w, v1.w), pack_bf16(v2.w, v3.w));
    }
    __syncthreads();

    // ---------------- gather + accumulate ----------------
    // One b128 per (output, k): 8 batch rows of column mask[o,k].
#define GSTEP(mi, wi) {                                                        \
        const int blk = bswz(mi);                                              \
        const uint4 d = *((const uint4*)lds + blk);                            \
        const float wv = (wi);                                                 \
        acc0 = fmaf(__uint_as_float(d.x << 16),          wv, acc0);            \
        acc1 = fmaf(__uint_as_float(d.x & 0xFFFF0000u),  wv, acc1);            \
        acc2 = fmaf(__uint_as_float(d.y << 16),          wv, acc2);            \
        acc3 = fmaf(__uint_as_float(d.y & 0xFFFF0000u),  wv, acc3);            \
        acc4 = fmaf(__uint_as_float(d.z << 16),          wv, acc4);            \
        acc5 = fmaf(__uint_as_float(d.z & 0xFFFF0000u),  wv, acc5);            \
        acc6 = fmaf(__uint_as_float(d.w << 16),          wv, acc6);            \
        acc7 = fmaf(__uint_as_float(d.w & 0xFFFF0000u),  wv, acc7);            \
    }

    const int obase = tid * O_PER_THREAD;
    #pragma unroll 1
    for (int i = 0; i < O_PER_THREAD; ++i) {
        const int o = obase + i;
        const float bv = bias[o];
        float acc0 = bv, acc1 = bv, acc2 = bv, acc3 = bv;
        float acc4 = bv, acc5 = bv, acc6 = bv, acc7 = bv;

        const int*   mp = M + (size_t)o * FAN_IN;
        const float* wp = W + (size_t)o * FAN_IN;

        #pragma unroll 2
        for (int kk = 0; kk < FAN_IN; kk += 4) {
            const int4   m4 = *(const int4*)(mp + kk);
            const float4 w4 = *(const float4*)(wp + kk);
            GSTEP(m4.x, w4.x);
            GSTEP(m4.y, w4.y);
            GSTEP(m4.z, w4.z);
            GSTEP(m4.w, w4.w);
        }

        float* op = out + (size_t)r0 * OUT_DIM + o;
        op[0 * OUT_DIM] = acc0;
        op[1 * OUT_DIM] = acc1;
        op[2 * OUT_DIM] = acc2;
        op[3 * OUT_DIM] = acc3;
        op[4 * OUT_DIM] = acc4;
        op[5 * OUT_DIM] = acc5;
        op[6 * OUT_DIM] = acc6;
        op[7 * OUT_DIM] = acc7;
    }
#undef GSTEP
}

extern "C" void kernel_launch(void* const* d_in, const int* in_sizes, int n_in,
                              void* d_out, int out_size, void* d_ws, size_t ws_size,
                              hipStream_t stream) {
    const float* inp  = (const float*)d_in[0];
    const float* W    = (const float*)d_in[1];
    const int*   M    = (const int*)d_in[2];
    const float* bias = (const float*)d_in[3];
    float* out = (float*)d_out;

    const int n_rows = in_sizes[0] / IN_DIM;          // 4096
    dim3 grid(n_rows / ROWS), block(NTHREADS);
    ffi_sparse_kernel<<<grid, block, 0, stream>>>(inp, W, M, bias, out);
}

// Round 3
// 157.117 us; speedup vs baseline: 1.1846x; 1.1846x over previous
//
#include <hip/hip_runtime.h>

#define IN_DIM   4096
#define OUT_DIM  4096
#define FAN_IN   64
#define ROWS     8                       // batch rows staged per block
#define NTHREADS 512
#define O_PER_THREAD (OUT_DIM / NTHREADS) // 8 output columns per thread

// Bijective 16B-block swizzle: within each 8-col group, XOR low bits by group id.
// Spreads ds bank-start groups for both staging writes and gather reads.
__device__ __forceinline__ int bswz(int m) {
    return (m & ~7) | ((m ^ (m >> 3)) & 7);
}

// round-to-nearest-even-ish f32->bf16, packed pair (a=lo, b=hi)
__device__ __forceinline__ unsigned int pack_bf16(float a, float b) {
    unsigned int ua = __float_as_uint(a);
    ua += 0x7FFFu + ((ua >> 16) & 1u);
    unsigned int ub = __float_as_uint(b);
    ub += 0x7FFFu + ((ub >> 16) & 1u);
    return (ua >> 16) | (ub & 0xFFFF0000u);
}

__global__ __launch_bounds__(NTHREADS, 4)
void ffi_sparse_kernel(const float* __restrict__ inp,
                       const float* __restrict__ W,
                       const int*   __restrict__ M,
                       const float* __restrict__ bias,
                       float* __restrict__ out)
{
    // [col][8 rows] as packed bf16 pairs: 4 uints (16 B) per column. 64 KiB.
    __shared__ unsigned int lds[IN_DIM * ROWS / 2];

    const int tid = threadIdx.x;
    const int r0  = blockIdx.x * ROWS;

    // ---------------- stage: 8 rows x 4096 cols, f32 -> bf16, transpose ----------------
    // Each iteration handles a 4x4 tile (4 rows x 4 cols = 16 elements).
    // Total tiles = ROWS*IN_DIM/16 = 2048 -> 4 iterations at 512 threads.
    #pragma unroll
    for (int t = 0; t < (ROWS * IN_DIM / 16) / NTHREADS; ++t) {   // 4 iterations
        const int tile = tid + t * NTHREADS;     // 0..2047
        const int rblk = tile >> 10;             // 0..1 -> rows rblk*4 .. rblk*4+3
        const int c4   = (tile & 1023) << 2;     // column base 0..4092
        const float* src = inp + (size_t)(r0 + rblk * 4) * IN_DIM + c4;
        const float4 v0 = *(const float4*)(src);
        const float4 v1 = *(const float4*)(src + IN_DIM);
        const float4 v2 = *(const float4*)(src + 2 * IN_DIM);
        const float4 v3 = *(const float4*)(src + 3 * IN_DIM);

        unsigned int* p;
        p = lds + bswz(c4 + 0) * 4 + rblk * 2;
        *(uint2*)p = make_uint2(pack_bf16(v0.x, v1.x), pack_bf16(v2.x, v3.x));
        p = lds + bswz(c4 + 1) * 4 + rblk * 2;
        *(uint2*)p = make_uint2(pack_bf16(v0.y, v1.y), pack_bf16(v2.y, v3.y));
        p = lds + bswz(c4 + 2) * 4 + rblk * 2;
        *(uint2*)p = make_uint2(pack_bf16(v0.z, v1.z), pack_bf16(v2.z, v3.z));
        p = lds + bswz(c4 + 3) * 4 + rblk * 2;
        *(uint2*)p = make_uint2(pack_bf16(v0.w, v1.w), pack_bf16(v2.w, v3.w));
    }
    __syncthreads();

    // ---------------- gather + accumulate ----------------
    // One b128 per (output, k): 8 batch rows of column mask[o,k].
#define GSTEP(mi, wi) {                                                        \
        const int blk = bswz(mi);                                              \
        const uint4 d = *((const uint4*)lds + blk);                            \
        const float wv = (wi);                                                 \
        acc0 = fmaf(__uint_as_float(d.x << 16),          wv, acc0);            \
        acc1 = fmaf(__uint_as_float(d.x & 0xFFFF0000u),  wv, acc1);            \
        acc2 = fmaf(__uint_as_float(d.y << 16),          wv, acc2);            \
        acc3 = fmaf(__uint_as_float(d.y & 0xFFFF0000u),  wv, acc3);            \
        acc4 = fmaf(__uint_as_float(d.z << 16),          wv, acc4);            \
        acc5 = fmaf(__uint_as_float(d.z & 0xFFFF0000u),  wv, acc5);            \
        acc6 = fmaf(__uint_as_float(d.w << 16),          wv, acc6);            \
        acc7 = fmaf(__uint_as_float(d.w & 0xFFFF0000u),  wv, acc7);            \
    }

    // Cyclic output mapping: o = tid + i*NTHREADS, so consecutive lanes own
    // consecutive output columns -> fully coalesced 4B stores (256 B/wave/row).
    // (Blocked mapping had lanes 32 B apart -> 8x HBM write amplification.)
    #pragma unroll 1
    for (int i = 0; i < O_PER_THREAD; ++i) {
        const int o = tid + i * NTHREADS;
        const float bv = bias[o];
        float acc0 = bv, acc1 = bv, acc2 = bv, acc3 = bv;
        float acc4 = bv, acc5 = bv, acc6 = bv, acc7 = bv;

        const int*   mp = M + (size_t)o * FAN_IN;
        const float* wp = W + (size_t)o * FAN_IN;

        #pragma unroll 2
        for (int kk = 0; kk < FAN_IN; kk += 4) {
            const int4   m4 = *(const int4*)(mp + kk);
            const float4 w4 = *(const float4*)(wp + kk);
            GSTEP(m4.x, w4.x);
            GSTEP(m4.y, w4.y);
            GSTEP(m4.z, w4.z);
            GSTEP(m4.w, w4.w);
        }

        float* op = out + (size_t)r0 * OUT_DIM + o;
        op[0 * OUT_DIM] = acc0;
        op[1 * OUT_DIM] = acc1;
        op[2 * OUT_DIM] = acc2;
        op[3 * OUT_DIM] = acc3;
        op[4 * OUT_DIM] = acc4;
        op[5 * OUT_DIM] = acc5;
        op[6 * OUT_DIM] = acc6;
        op[7 * OUT_DIM] = acc7;
    }
#undef GSTEP
}

extern "C" void kernel_launch(void* const* d_in, const int* in_sizes, int n_in,
                              void* d_out, int out_size, void* d_ws, size_t ws_size,
                              hipStream_t stream) {
    const float* inp  = (const float*)d_in[0];
    const float* W    = (const float*)d_in[1];
    const int*   M    = (const int*)d_in[2];
    const float* bias = (const float*)d_in[3];
    float* out = (float*)d_out;

    const int n_rows = in_sizes[0] / IN_DIM;          // 4096
    dim3 grid(n_rows / ROWS), block(NTHREADS);
    ffi_sparse_kernel<<<grid, block, 0, stream>>>(inp, W, M, bias, out);
}